// Round 16
// baseline (1582.012 us; speedup 1.0000x reference)
//
#include <hip/hip_runtime.h>

#define B_ 128
#define T_ 256
#define IN_ 256
#define H_ 512
#define G4_ 2048   // 4*H
#define TC_ 16     // time chunk
#define NCHUNK_ 16

typedef __attribute__((ext_vector_type(8))) short short8v;   // 8 bf16
typedef __attribute__((ext_vector_type(4))) float float4v;
typedef unsigned short ushort_t;

// ---- workspace layout (float offsets) ---- (~26MB total)
// XG layout: [B][TC][512][4] bf16 (gate-interleaved: one 8B load per (b,t,col))
static constexpr size_t OFF_XG0 = 0;                                    // B*TC*G4 bf16
static constexpr size_t OFF_XG1 = OFF_XG0 + (size_t)B_ * TC_ * G4_ / 2;
static constexpr size_t OFF_H0C = OFF_XG1 + (size_t)B_ * TC_ * G4_ / 2; // B*TC*H bf16
static constexpr size_t OFF_HB0 = OFF_H0C + (size_t)B_ * TC_ * H_ / 2;  // 2 slots bf16
static constexpr size_t OFF_HB1 = OFF_HB0 + (size_t)B_ * H_;
static constexpr size_t OFF_C0  = OFF_HB1 + (size_t)B_ * H_;            // B*H fp32
static constexpr size_t OFF_C1  = OFF_C0 + (size_t)B_ * H_;
static constexpr size_t OFF_WF0 = OFF_C1 + (size_t)B_ * H_;             // W_hh frags bf16
static constexpr size_t OFF_WF1 = OFF_WF0 + (size_t)G4_ * H_ / 2;
static constexpr size_t OFF_WI0 = OFF_WF1 + (size_t)G4_ * H_ / 2;       // K=256 frags
static constexpr size_t OFF_WI1 = OFF_WI0 + (size_t)G4_ * IN_ / 2;      // K=512 frags
static constexpr size_t OFF_END = OFF_WI1 + (size_t)G4_ * H_ / 2;

// bf16 round-to-nearest-even from fp32
__device__ __forceinline__ unsigned int bfr(float f) {
  unsigned int u = __float_as_uint(f);
  return (u + 0x7fffu + ((u >> 16) & 1u)) >> 16;
}
__device__ __forceinline__ float bf2f(unsigned int u) {
  return __uint_as_float(u << 16);
}

// ============================================================================
// Pack W_hh [2048][512] fp32 -> bf16 MFMA B-fragments, gate-tiled order
// (ct,g,ks): lane l holds W[g*512+ct*16+(l&15)][ks*32+(l>>4)*8 .. +7].
// ============================================================================
__global__ __launch_bounds__(256) void pack_whh3(
    const float* __restrict__ W, uint4* __restrict__ WF) {
  const int idx = blockIdx.x * 256 + threadIdx.x;
  const int l  = idx & 63;
  const int ks = (idx >> 6) & 15;
  const int g  = (idx >> 10) & 3;
  const int ct = idx >> 12;
  const int row = g * H_ + ct * 16 + (l & 15);
  const int k0  = ks * 32 + (l >> 4) * 8;
  const float* s = W + (size_t)row * H_ + k0;
  uint4 o;
  o.x = bfr(s[0]) | (bfr(s[1]) << 16);
  o.y = bfr(s[2]) | (bfr(s[3]) << 16);
  o.z = bfr(s[4]) | (bfr(s[5]) << 16);
  o.w = bfr(s[6]) | (bfr(s[7]) << 16);
  WF[idx] = o;
}

// ============================================================================
// Pack W_ih [2048][K] fp32 -> bf16 MFMA B-fragments, plain n-tile order.
// ============================================================================
__global__ __launch_bounds__(256) void pack_wih(
    const float* __restrict__ W, uint4* __restrict__ WF, int K) {
  const int idx = blockIdx.x * 256 + threadIdx.x;
  const int ksn = K >> 5;
  const int l  = idx & 63;
  const int ks = (idx >> 6) & (ksn - 1);
  const int nt = idx >> 6 >> (K == 512 ? 4 : 3);
  const int row = nt * 16 + (l & 15);
  const int k0  = ks * 32 + (l >> 4) * 8;
  const float* s = W + (size_t)row * K + k0;
  uint4 o;
  o.x = bfr(s[0]) | (bfr(s[1]) << 16);
  o.y = bfr(s[2]) | (bfr(s[3]) << 16);
  o.z = bfr(s[4]) | (bfr(s[5]) << 16);
  o.w = bfr(s[6]) | (bfr(s[7]) << 16);
  WF[idx] = o;
}

// ============================================================================
// Device GEMM body (r12-verified math): C = A W^T + b1 + b2, bf16 out in
// gate-interleaved layout Cw[(m*512 + hcol)*4 + gate], gate = n>>9.
// arow = (m>>4)*T_A + t0 + (m&15). A fp32 (abf=0) or bf16 (abf=1).
// ============================================================================
__device__ __forceinline__ void gemm_dev(
    uint4* Ash, const void* Av, int abf, int K, int T_A, int t0,
    const short8v* WF, const float* b1, const float* b2,
    ushort_t* Cw, int gbid, int tid) {
  const int xcd = gbid & 7;
  const int q   = gbid >> 3;
  const int n0  = (xcd * 4 + (q & 3)) * 64;
  const int m0  = (q >> 2) * 64;
  const int ksn = K >> 5;
  const int npass = K >> 8;              // 1 (K=256) or 2 (K=512)

  const int lane = tid & 63;
  const int w = tid >> 6;
  const int ar = lane & 15;
  const int koct = lane >> 4;
  const int nt = (n0 >> 4) + w;
  const short8v* wf = WF + (size_t)nt * ksn * 64 + lane;
  float4v acc0 = {0,0,0,0}, acc1 = {0,0,0,0}, acc2 = {0,0,0,0}, acc3 = {0,0,0,0};

  for (int p = 0; p < npass; ++p) {
    if (p) __syncthreads();
    for (int idx = tid; idx < 2048; idx += 256) {
      const int r = idx >> 5, c = idx & 31;
      const int m = m0 + r;
      const size_t arow = (size_t)(m >> 4) * T_A + t0 + (m & 15);
      const size_t koff = (size_t)p * 256 + c * 8;
      uint4 val;
      if (abf) {
        val = *(const uint4*)((const ushort_t*)Av + arow * K + koff);
      } else {
        const float* ap = (const float*)Av + arow * K + koff;
        const float4 lo = *(const float4*)ap;
        const float4 hi = *(const float4*)(ap + 4);
        val.x = bfr(lo.x) | (bfr(lo.y) << 16);
        val.y = bfr(lo.z) | (bfr(lo.w) << 16);
        val.z = bfr(hi.x) | (bfr(hi.y) << 16);
        val.w = bfr(hi.z) | (bfr(hi.w) << 16);
      }
      Ash[(r << 5) + (c ^ (r & 7))] = val;
    }
    __syncthreads();
#pragma unroll 4
    for (int ksl = 0; ksl < 8; ++ksl) {
      const short8v bv = wf[(size_t)(p * 8 + ksl) * 64];
      const int cc = ksl * 4 + koct;
      const short8v a0 = *(const short8v*)&Ash[((ar +  0) << 5) + (cc ^ ((ar +  0) & 7))];
      const short8v a1 = *(const short8v*)&Ash[((ar + 16) << 5) + (cc ^ ((ar + 16) & 7))];
      const short8v a2 = *(const short8v*)&Ash[((ar + 32) << 5) + (cc ^ ((ar + 32) & 7))];
      const short8v a3 = *(const short8v*)&Ash[((ar + 48) << 5) + (cc ^ ((ar + 48) & 7))];
      acc0 = __builtin_amdgcn_mfma_f32_16x16x32_bf16(a0, bv, acc0, 0, 0, 0);
      acc1 = __builtin_amdgcn_mfma_f32_16x16x32_bf16(a1, bv, acc1, 0, 0, 0);
      acc2 = __builtin_amdgcn_mfma_f32_16x16x32_bf16(a2, bv, acc2, 0, 0, 0);
      acc3 = __builtin_amdgcn_mfma_f32_16x16x32_bf16(a3, bv, acc3, 0, 0, 0);
    }
  }
  const int dcol = lane & 15, drow = (lane >> 4) * 4;
  const int n = n0 + w * 16 + dcol;
  const int gate = n >> 9, hc = n & 511;
  const float bs = b1[n] + b2[n];
#pragma unroll
  for (int rr = 0; rr < 4; ++rr) {
    const float v[4] = {acc0[rr], acc1[rr], acc2[rr], acc3[rr]};
#pragma unroll
    for (int mb = 0; mb < 4; ++mb)
      Cw[((size_t)(m0 + mb * 16 + drow + rr) * 512 + hc) * 4 + gate] =
          (ushort_t)bfr(v[mb] + bs);
  }
}

// ============================================================================
// Dual-role GEMM dispatch: blocks [0,1024) -> XG1(prev chunk, from h0c) when
// do1; remaining 1024 -> XG0(this chunk, from x). (r14-verified driver.)
// ============================================================================
__global__ __launch_bounds__(256) void gemm_dual(
    const float* __restrict__ x, const short8v* __restrict__ WI0,
    const float* __restrict__ bi0, const float* __restrict__ bh0,
    ushort_t* __restrict__ xg0w, int t0,
    const ushort_t* __restrict__ h0c, const short8v* __restrict__ WI1,
    const float* __restrict__ bi1, const float* __restrict__ bh1,
    ushort_t* __restrict__ xg1w, int do1) {
  __shared__ uint4 Ash[2048];
  int bid = blockIdx.x;
  if (do1) {
    if (bid < 1024) {
      gemm_dev(Ash, h0c, 1, H_, TC_, 0, WI1, bi1, bh1, xg1w, bid, threadIdx.x);
      return;
    }
    bid -= 1024;
  }
  gemm_dev(Ash, x, 0, IN_, T_, t0, WI0, bi0, bh0, xg0w, bid, threadIdx.x);
}

// ============================================================================
// Fused 2-layer MFMA LSTM step — wide-block variant: 512 threads / 8 waves,
// block = 16 batches x 32 hcols x 4 gates (2 ct16-subtiles x 4 gate-waves).
// Halves block count -> halves h re-read traffic. MFMA chain identical to the
// r8-verified form (16 x mfma_16x16x32 over K=512 per wave).
// mode 0: 256 blocks (128 L0 + 128 L1); 1: 128 L0; 2: 128 L1.
// ============================================================================
__global__ __launch_bounds__(512) void lstm_step2(
    const short8v* __restrict__ WF0, const ushort_t* __restrict__ xg0,
    const ushort_t* __restrict__ h0p, ushort_t* __restrict__ h0n,
    float* __restrict__ cs0, ushort_t* __restrict__ h0c,
    const short8v* __restrict__ WF1, const ushort_t* __restrict__ xg1,
    const ushort_t* __restrict__ h1p, ushort_t* __restrict__ h1n,
    float* __restrict__ cs1, int tl, int mode) {
  __shared__ ushort_t hsh[16 * 512];        // 16KB h tile (bf16, chunk-swizzled)
  __shared__ float gl[2][4][16][17];        // gate tiles per ct-subtile
  const int bid = blockIdx.x;
  int lbid = bid, layer;
  if (mode == 0) { layer = bid >> 7; lbid = bid & 127; } else layer = mode - 1;
  const int xcd  = lbid & 7;
  const int q    = lbid >> 3;           // 0..15
  const int ct32 = xcd * 2 + (q & 1);   // 16 tiles of 32 hcols
  const int bt   = q >> 1;              // 0..7
  const int b0   = bt * 16;

  const short8v* WF; const ushort_t* xg; const ushort_t* hprev;
  ushort_t* hnext; float* cst;
  if (layer == 0) { WF = WF0; xg = xg0; hprev = h0p; hnext = h0n; cst = cs0; }
  else            { WF = WF1; xg = xg1; hprev = h1p; hnext = h1n; cst = cs1; }

  const int tid = threadIdx.x;
  // tail identity + prefetch (all 512 threads: 16 b x 32 col)
  const int tb = tid >> 5, thc = tid & 31;
  const int bb = b0 + tb;
  const int hcol = ct32 * 32 + thc;
  const uint2 xq = *(const uint2*)(xg + (((size_t)bb * TC_ + tl) * 512 + hcol) * 4);
  const float xi  = bf2f(xq.x & 0xffffu);
  const float xf  = bf2f(xq.x >> 16);
  const float xgv = bf2f(xq.y & 0xffffu);
  const float xo  = bf2f(xq.y >> 16);
  const float cin = cst[(size_t)bb * H_ + hcol];

  // stage h tile: 16 rows x 64 chunks(16B bf16x8), swizzle chunk c -> c^(r&7)
  const uint4* hp4 = (const uint4*)hprev + (size_t)b0 * 64;
#pragma unroll
  for (int j = 0; j < 2; ++j) {
    const int idx = tid + j * 512;
    const int r = idx >> 6, c = idx & 63;
    *(uint4*)&hsh[(r * 64 + (c ^ (r & 7))) * 8] = hp4[(size_t)r * 64 + c];
  }
  __syncthreads();

  // MFMA: wave (cs, g) -> gate g's 16x16 tile for ct16 = ct32*2+cs, K=512
  const int lane = tid & 63;
  const int w  = tid >> 6;
  const int cs = w >> 2;
  const int g  = w & 3;
  const int ar = lane & 15;
  const int koct = lane >> 4;
  float4v acc = {0.f, 0.f, 0.f, 0.f};
  const short8v* wf = WF + ((size_t)((ct32 * 2 + cs) * 4 + g) * 16) * 64 + lane;
#pragma unroll
  for (int ks = 0; ks < 16; ++ks) {
    const int c16 = ks * 4 + koct;
    const short8v av = *(const short8v*)&hsh[(ar * 64 + (c16 ^ (ar & 7))) * 8];
    const short8v bv = wf[(size_t)ks * 64];
    acc = __builtin_amdgcn_mfma_f32_16x16x32_bf16(av, bv, acc, 0, 0, 0);
  }
  // D layout: col = lane&15, row = (lane>>4)*4 + reg
  const int drow = (lane >> 4) * 4, dcol = lane & 15;
#pragma unroll
  for (int rr = 0; rr < 4; ++rr) gl[cs][g][drow + rr][dcol] = acc[rr];
  __syncthreads();

  // tail: thread (tb, thc) combines 4 gates of its ct-subtile
  {
    const int cs_t = thc >> 4, t16 = thc & 15;
    const float gi = gl[cs_t][0][tb][t16] + xi;
    const float gf = gl[cs_t][1][tb][t16] + xf;
    const float gg = gl[cs_t][2][tb][t16] + xgv;
    const float go = gl[cs_t][3][tb][t16] + xo;
    const float iv = 1.f / (1.f + __expf(-gi));
    const float fv = 1.f / (1.f + __expf(-gf));
    const float gv = tanhf(gg);
    const float ov = 1.f / (1.f + __expf(-go));
    const float cn = fv * cin + iv * gv;
    const float hv = ov * tanhf(cn);
    cst[(size_t)bb * H_ + hcol] = cn;
    const ushort_t hb = (ushort_t)bfr(hv);
    hnext[(size_t)bb * H_ + hcol] = hb;
    if (layer == 0) h0c[((size_t)bb * TC_ + tl) * H_ + hcol] = hb;
  }
}

// ============================================================================
// Final FC (10 classes) + log_softmax. One wave per batch row; h is bf16.
// ============================================================================
__global__ __launch_bounds__(64) void fc_logsoftmax(
    const ushort_t* __restrict__ h, const float* __restrict__ Wfc,
    const float* __restrict__ bfc, float* __restrict__ out) {
  const int b = blockIdx.x, lane = threadIdx.x;
  const uint4 hv = *(const uint4*)(h + (size_t)b * H_ + lane * 8);
  const float hf[8] = {
      bf2f(hv.x & 0xffffu), bf2f(hv.x >> 16), bf2f(hv.y & 0xffffu), bf2f(hv.y >> 16),
      bf2f(hv.z & 0xffffu), bf2f(hv.z >> 16), bf2f(hv.w & 0xffffu), bf2f(hv.w >> 16)};
  float logits[10];
#pragma unroll
  for (int cc = 0; cc < 10; ++cc) {
    const float* wr = Wfc + (size_t)cc * H_ + lane * 8;
    const float4 w0 = *(const float4*)wr;
    const float4 w1 = *(const float4*)(wr + 4);
    float v = hf[0] * w0.x + hf[1] * w0.y + hf[2] * w0.z + hf[3] * w0.w +
              hf[4] * w1.x + hf[5] * w1.y + hf[6] * w1.z + hf[7] * w1.w;
#pragma unroll
    for (int off = 32; off; off >>= 1) v += __shfl_xor(v, off);
    logits[cc] = v + bfc[cc];
  }
  float m = logits[0];
#pragma unroll
  for (int cc = 1; cc < 10; ++cc) m = fmaxf(m, logits[cc]);
  float s = 0.f;
#pragma unroll
  for (int cc = 0; cc < 10; ++cc) s += __expf(logits[cc] - m);
  const float lse = m + __logf(s);
  if (lane < 10) out[(size_t)b * 10 + lane] = logits[lane] - lse;
}

// ============================================================================
extern "C" void kernel_launch(void* const* d_in, const int* in_sizes, int n_in,
                              void* d_out, int out_size, void* d_ws, size_t ws_size,
                              hipStream_t stream) {
  const float* x    = (const float*)d_in[0];
  const float* Wih0 = (const float*)d_in[1];
  const float* Whh0 = (const float*)d_in[2];
  const float* bih0 = (const float*)d_in[3];
  const float* bhh0 = (const float*)d_in[4];
  const float* Wih1 = (const float*)d_in[5];
  const float* Whh1 = (const float*)d_in[6];
  const float* bih1 = (const float*)d_in[7];
  const float* bhh1 = (const float*)d_in[8];
  const float* Wfc  = (const float*)d_in[9];
  const float* bfc  = (const float*)d_in[10];

  float* ws = (float*)d_ws;
  ushort_t* XG0 = (ushort_t*)(ws + OFF_XG0);
  ushort_t* XG1 = (ushort_t*)(ws + OFF_XG1);
  ushort_t* h0c = (ushort_t*)(ws + OFF_H0C);
  ushort_t* hb0 = (ushort_t*)(ws + OFF_HB0);
  ushort_t* hb1 = (ushort_t*)(ws + OFF_HB1);
  float* c0 = ws + OFF_C0;
  float* c1 = ws + OFF_C1;
  short8v* wf0 = (short8v*)(ws + OFF_WF0);
  short8v* wf1 = (short8v*)(ws + OFF_WF1);
  short8v* wi0 = (short8v*)(ws + OFF_WI0);
  short8v* wi1 = (short8v*)(ws + OFF_WI1);

  // zero h ping-pongs + c states; pack all weights to MFMA fragments
  hipMemsetAsync(hb0, 0, (OFF_WF0 - OFF_HB0) * sizeof(float), stream);
  pack_whh3<<<512, 256, 0, stream>>>(Whh0, (uint4*)wf0);
  pack_whh3<<<512, 256, 0, stream>>>(Whh1, (uint4*)wf1);
  pack_wih<<<256, 256, 0, stream>>>(Wih0, (uint4*)wi0, IN_);
  pack_wih<<<512, 256, 0, stream>>>(Wih1, (uint4*)wi1, H_);

  const size_t BHu = (size_t)B_ * H_;  // bf16 slot stride
  for (int ch = 0; ch < NCHUNK_; ++ch) {
    const int t0 = ch * TC_;
    // one GEMM dispatch per chunk: XG1(ch-1) from h0c (if ch>0) + XG0(ch)
    const int do1 = (ch > 0) ? 1 : 0;
    gemm_dual<<<do1 ? 2048 : 1024, 256, 0, stream>>>(
        x, wi0, bih0, bhh0, XG0, t0,
        h0c, wi1, bih1, bhh1, XG1, do1);
    for (int t = 0; t < TC_; ++t) {
      const int sg0 = t0 + t + 1;        // L0 global step (1-based)
      const int sg1 = sg0 - TC_;         // L1 global step (prev chunk)
      const int mode = (ch == 0) ? 1 : 0;
      const int nblk = (ch == 0) ? 128 : 256;
      lstm_step2<<<nblk, 512, 0, stream>>>(
          wf0, XG0, hb0 + ((sg0 - 1) & 1) * BHu, hb0 + (sg0 & 1) * BHu, c0, h0c,
          wf1, XG1, hb1 + ((sg1 - 1) & 1) * BHu, hb1 + (sg1 & 1) * BHu, c1,
          t, mode);
    }
  }
  // pipeline drain: XG1(15) then L1-only steps over the last chunk
  gemm_dual<<<1024, 256, 0, stream>>>(
      x, wi0, bih0, bhh0, XG0, -1,       // t0<0 unused: grid covers XG1 only
      h0c, wi1, bih1, bhh1, XG1, 1);
  for (int t = 0; t < TC_; ++t) {
    const int sg1 = (NCHUNK_ - 1) * TC_ + t + 1;
    lstm_step2<<<128, 512, 0, stream>>>(
        wf0, XG0, hb0, hb0, c0, h0c,
        wf1, XG1, hb1 + ((sg1 - 1) & 1) * BHu, hb1 + (sg1 & 1) * BHu, c1,
        t, 2);
  }
  // T=256 even -> final h1 in bf16 slot 0
  fc_logsoftmax<<<dim3(B_), 64, 0, stream>>>(hb1, Wfc, bfc, (float*)d_out);
}

// Round 17
// 1363.663 us; speedup vs baseline: 1.1601x; 1.1601x over previous
//
#include <hip/hip_runtime.h>

#define B_ 128
#define T_ 256
#define IN_ 256
#define H_ 512
#define G4_ 2048   // 4*H
#define TC_ 16     // time chunk
#define NCHUNK_ 16

typedef __attribute__((ext_vector_type(8))) short short8v;   // 8 bf16
typedef __attribute__((ext_vector_type(4))) float float4v;
typedef unsigned short ushort_t;

// ---- workspace layout (float offsets) ---- (~26MB total)
// XG layout: [B][TC][512][4] bf16 — gate-interleaved via PERMUTED WEIGHT
// PACKING (GEMM C-writes stay contiguous; scan reads one 8B chunk per col).
static constexpr size_t OFF_XG0 = 0;                                    // B*TC*G4 bf16
static constexpr size_t OFF_XG1 = OFF_XG0 + (size_t)B_ * TC_ * G4_ / 2;
static constexpr size_t OFF_H0C = OFF_XG1 + (size_t)B_ * TC_ * G4_ / 2; // B*TC*H bf16
static constexpr size_t OFF_HB0 = OFF_H0C + (size_t)B_ * TC_ * H_ / 2;  // 2 slots bf16
static constexpr size_t OFF_HB1 = OFF_HB0 + (size_t)B_ * H_;
static constexpr size_t OFF_C0  = OFF_HB1 + (size_t)B_ * H_;            // B*H fp32
static constexpr size_t OFF_C1  = OFF_C0 + (size_t)B_ * H_;
static constexpr size_t OFF_WF0 = OFF_C1 + (size_t)B_ * H_;             // W_hh frags bf16
static constexpr size_t OFF_WF1 = OFF_WF0 + (size_t)G4_ * H_ / 2;
static constexpr size_t OFF_WI0 = OFF_WF1 + (size_t)G4_ * H_ / 2;       // K=256 frags
static constexpr size_t OFF_WI1 = OFF_WI0 + (size_t)G4_ * IN_ / 2;      // K=512 frags
static constexpr size_t OFF_END = OFF_WI1 + (size_t)G4_ * H_ / 2;

// bf16 round-to-nearest-even from fp32
__device__ __forceinline__ unsigned int bfr(float f) {
  unsigned int u = __float_as_uint(f);
  return (u + 0x7fffu + ((u >> 16) & 1u)) >> 16;
}
__device__ __forceinline__ float bf2f(unsigned int u) {
  return __uint_as_float(u << 16);
}

// ============================================================================
// Pack W_hh [2048][512] fp32 -> bf16 MFMA B-fragments, gate-tiled order
// (ct,g,ks): lane l holds W[g*512+ct*16+(l&15)][ks*32+(l>>4)*8 .. +7].
// (unchanged from r8..r14 — scan weight side)
// ============================================================================
__global__ __launch_bounds__(256) void pack_whh3(
    const float* __restrict__ W, uint4* __restrict__ WF) {
  const int idx = blockIdx.x * 256 + threadIdx.x;
  const int l  = idx & 63;
  const int ks = (idx >> 6) & 15;
  const int g  = (idx >> 10) & 3;
  const int ct = idx >> 12;
  const int row = g * H_ + ct * 16 + (l & 15);
  const int k0  = ks * 32 + (l >> 4) * 8;
  const float* s = W + (size_t)row * H_ + k0;
  uint4 o;
  o.x = bfr(s[0]) | (bfr(s[1]) << 16);
  o.y = bfr(s[2]) | (bfr(s[3]) << 16);
  o.z = bfr(s[4]) | (bfr(s[5]) << 16);
  o.w = bfr(s[6]) | (bfr(s[7]) << 16);
  WF[idx] = o;
}

// ============================================================================
// Pack W_ih [2048][K] fp32 -> bf16 MFMA B-fragments, PERMUTED n-tile order:
// output col n' maps to weight row (n'&3)*512 + (n'>>2), so the GEMM's
// contiguous C-write produces gate-interleaved XG for free.
// frag (nt, ks): lane l holds W[row(nt*16+(l&15))][ks*32+(l>>4)*8 .. +7].
// ============================================================================
__global__ __launch_bounds__(256) void pack_wih(
    const float* __restrict__ W, uint4* __restrict__ WF, int K) {
  const int idx = blockIdx.x * 256 + threadIdx.x;
  const int ksn = K >> 5;
  const int l  = idx & 63;
  const int ks = (idx >> 6) & (ksn - 1);
  const int nt = idx >> 6 >> (K == 512 ? 4 : 3);
  const int np = nt * 16 + (l & 15);          // interleaved output col
  const int row = (np & 3) * H_ + (np >> 2);  // gate-major weight row
  const int k0  = ks * 32 + (l >> 4) * 8;
  const float* s = W + (size_t)row * K + k0;
  uint4 o;
  o.x = bfr(s[0]) | (bfr(s[1]) << 16);
  o.y = bfr(s[2]) | (bfr(s[3]) << 16);
  o.z = bfr(s[4]) | (bfr(s[5]) << 16);
  o.w = bfr(s[6]) | (bfr(s[7]) << 16);
  WF[idx] = o;
}

// ============================================================================
// Device GEMM body (r12/r14-verified): C[m][n'] = sum_k A(m)[k]W(n')[k]+b,
// bf16 out, CONTIGUOUS write (r14-identical). Bias indexed through the
// gate-major permutation n_act = (n'&3)*512 + (n'>>2).
// arow = (m>>4)*T_A + t0 + (m&15). A fp32 (abf=0) or bf16 (abf=1).
// ============================================================================
__device__ __forceinline__ void gemm_dev(
    uint4* Ash, const void* Av, int abf, int K, int T_A, int t0,
    const short8v* WF, const float* b1, const float* b2,
    ushort_t* Cw, int gbid, int tid) {
  const int xcd = gbid & 7;
  const int q   = gbid >> 3;
  const int n0  = (xcd * 4 + (q & 3)) * 64;
  const int m0  = (q >> 2) * 64;
  const int ksn = K >> 5;
  const int npass = K >> 8;              // 1 (K=256) or 2 (K=512)

  const int lane = tid & 63;
  const int w = tid >> 6;
  const int ar = lane & 15;
  const int koct = lane >> 4;
  const int nt = (n0 >> 4) + w;
  const short8v* wf = WF + (size_t)nt * ksn * 64 + lane;
  float4v acc0 = {0,0,0,0}, acc1 = {0,0,0,0}, acc2 = {0,0,0,0}, acc3 = {0,0,0,0};

  for (int p = 0; p < npass; ++p) {
    if (p) __syncthreads();
    for (int idx = tid; idx < 2048; idx += 256) {
      const int r = idx >> 5, c = idx & 31;
      const int m = m0 + r;
      const size_t arow = (size_t)(m >> 4) * T_A + t0 + (m & 15);
      const size_t koff = (size_t)p * 256 + c * 8;
      uint4 val;
      if (abf) {
        val = *(const uint4*)((const ushort_t*)Av + arow * K + koff);
      } else {
        const float* ap = (const float*)Av + arow * K + koff;
        const float4 lo = *(const float4*)ap;
        const float4 hi = *(const float4*)(ap + 4);
        val.x = bfr(lo.x) | (bfr(lo.y) << 16);
        val.y = bfr(lo.z) | (bfr(lo.w) << 16);
        val.z = bfr(hi.x) | (bfr(hi.y) << 16);
        val.w = bfr(hi.z) | (bfr(hi.w) << 16);
      }
      Ash[(r << 5) + (c ^ (r & 7))] = val;
    }
    __syncthreads();
#pragma unroll 4
    for (int ksl = 0; ksl < 8; ++ksl) {
      const short8v bv = wf[(size_t)(p * 8 + ksl) * 64];
      const int cc = ksl * 4 + koct;
      const short8v a0 = *(const short8v*)&Ash[((ar +  0) << 5) + (cc ^ ((ar +  0) & 7))];
      const short8v a1 = *(const short8v*)&Ash[((ar + 16) << 5) + (cc ^ ((ar + 16) & 7))];
      const short8v a2 = *(const short8v*)&Ash[((ar + 32) << 5) + (cc ^ ((ar + 32) & 7))];
      const short8v a3 = *(const short8v*)&Ash[((ar + 48) << 5) + (cc ^ ((ar + 48) & 7))];
      acc0 = __builtin_amdgcn_mfma_f32_16x16x32_bf16(a0, bv, acc0, 0, 0, 0);
      acc1 = __builtin_amdgcn_mfma_f32_16x16x32_bf16(a1, bv, acc1, 0, 0, 0);
      acc2 = __builtin_amdgcn_mfma_f32_16x16x32_bf16(a2, bv, acc2, 0, 0, 0);
      acc3 = __builtin_amdgcn_mfma_f32_16x16x32_bf16(a3, bv, acc3, 0, 0, 0);
    }
  }
  const int dcol = lane & 15, drow = (lane >> 4) * 4;
  const int n = n0 + w * 16 + dcol;               // interleaved col n'
  const int n_act = (n & 3) * 512 + (n >> 2);     // gate-major bias index
  const float bs = b1[n_act] + b2[n_act];
  ushort_t* Cb = Cw + (size_t)(m0 + drow) * G4_ + n;
#pragma unroll
  for (int rr = 0; rr < 4; ++rr) {
    Cb[(size_t)(0 + rr) * G4_]  = (ushort_t)bfr(acc0[rr] + bs);
    Cb[(size_t)(16 + rr) * G4_] = (ushort_t)bfr(acc1[rr] + bs);
    Cb[(size_t)(32 + rr) * G4_] = (ushort_t)bfr(acc2[rr] + bs);
    Cb[(size_t)(48 + rr) * G4_] = (ushort_t)bfr(acc3[rr] + bs);
  }
}

// ============================================================================
// Dual-role GEMM dispatch (r14-verified driver): blocks [0,1024) -> XG1(prev
// chunk, from h0c) when do1; remaining 1024 -> XG0(this chunk, from x).
// ============================================================================
__global__ __launch_bounds__(256) void gemm_dual(
    const float* __restrict__ x, const short8v* __restrict__ WI0,
    const float* __restrict__ bi0, const float* __restrict__ bh0,
    ushort_t* __restrict__ xg0w, int t0,
    const ushort_t* __restrict__ h0c, const short8v* __restrict__ WI1,
    const float* __restrict__ bi1, const float* __restrict__ bh1,
    ushort_t* __restrict__ xg1w, int do1) {
  __shared__ uint4 Ash[2048];
  int bid = blockIdx.x;
  if (do1) {
    if (bid < 1024) {
      gemm_dev(Ash, h0c, 1, H_, TC_, 0, WI1, bi1, bh1, xg1w, bid, threadIdx.x);
      return;
    }
    bid -= 1024;
  }
  gemm_dev(Ash, x, 0, IN_, T_, t0, WI0, bi0, bh0, xg0w, bid, threadIdx.x);
}

// ============================================================================
// Fused 2-layer MFMA LSTM step (r14-verified 4-wave form; xg gate-interleaved
// -> ONE coalesced 8B load per thread instead of 4 scattered 2B loads).
// mode 0: 512 blocks (L0+L1); 1: 256 L0; 2: 256 L1. 256 threads / 4 waves.
// ============================================================================
__global__ __launch_bounds__(256) void lstm_step2(
    const short8v* __restrict__ WF0, const ushort_t* __restrict__ xg0,
    const ushort_t* __restrict__ h0p, ushort_t* __restrict__ h0n,
    float* __restrict__ cs0, ushort_t* __restrict__ h0c,
    const short8v* __restrict__ WF1, const ushort_t* __restrict__ xg1,
    const ushort_t* __restrict__ h1p, ushort_t* __restrict__ h1n,
    float* __restrict__ cs1, int tl, int mode) {
  __shared__ ushort_t hsh[16 * 512];        // 16KB h tile (bf16, chunk-swizzled)
  __shared__ float gl[4][16][17];           // gate tiles for tail
  const int bid = blockIdx.x;
  const int layer = (mode == 0) ? (bid >> 8) : (mode - 1);
  const int xcd = bid & 7;
  const int ctl = (bid >> 3) & 3;
  const int bt  = (bid >> 5) & 7;
  const int ct  = xcd * 4 + ctl;
  const int b0  = bt * 16;

  const short8v* WF; const ushort_t* xg; const ushort_t* hprev;
  ushort_t* hnext; float* cst;
  if (layer == 0) { WF = WF0; xg = xg0; hprev = h0p; hnext = h0n; cst = cs0; }
  else            { WF = WF1; xg = xg1; hprev = h1p; hnext = h1n; cst = cs1; }

  const int tid = threadIdx.x;
  const int tb = tid >> 4, thc = tid & 15;
  const int bb = b0 + tb;
  const int hcol = ct * 16 + thc;
  // gate-interleaved XG: one 8B load -> all 4 gate pre-activations
  const uint2 xq = *(const uint2*)(xg + (((size_t)bb * TC_ + tl) * 512 + hcol) * 4);
  const float xi  = bf2f(xq.x & 0xffffu);
  const float xf  = bf2f(xq.x >> 16);
  const float xgv = bf2f(xq.y & 0xffffu);
  const float xo  = bf2f(xq.y >> 16);
  const float cin = cst[(size_t)bb * H_ + hcol];

  // stage h tile: 16 rows x 64 chunks(16B bf16x8), swizzle chunk c -> c^(r&7)
  const uint4* hp4 = (const uint4*)hprev + (size_t)b0 * 64;
#pragma unroll
  for (int j = 0; j < 4; ++j) {
    const int idx = tid + j * 256;
    const int r = idx >> 6, c = idx & 63;
    *(uint4*)&hsh[(r * 64 + (c ^ (r & 7))) * 8] = hp4[(size_t)r * 64 + c];
  }
  __syncthreads();

  const int lane = tid & 63;
  const int g = tid >> 6;
  const int ar = lane & 15;
  const int koct = lane >> 4;
  float4v acc = {0.f, 0.f, 0.f, 0.f};
  const short8v* wf = WF + ((size_t)(ct * 4 + g) * 16) * 64 + lane;
#pragma unroll
  for (int ks = 0; ks < 16; ++ks) {
    const int c16 = ks * 4 + koct;
    const short8v av = *(const short8v*)&hsh[(ar * 64 + (c16 ^ (ar & 7))) * 8];
    const short8v bv = wf[(size_t)ks * 64];
    acc = __builtin_amdgcn_mfma_f32_16x16x32_bf16(av, bv, acc, 0, 0, 0);
  }
  // D layout: col = lane&15, row = (lane>>4)*4 + reg
  const int drow = (lane >> 4) * 4, dcol = lane & 15;
#pragma unroll
  for (int rr = 0; rr < 4; ++rr) gl[g][drow + rr][dcol] = acc[rr];
  __syncthreads();

  {
    const float gi = gl[0][tb][thc] + xi;
    const float gf = gl[1][tb][thc] + xf;
    const float gg = gl[2][tb][thc] + xgv;
    const float go = gl[3][tb][thc] + xo;
    const float iv = 1.f / (1.f + __expf(-gi));
    const float fv = 1.f / (1.f + __expf(-gf));
    const float gv = tanhf(gg);
    const float ov = 1.f / (1.f + __expf(-go));
    const float cn = fv * cin + iv * gv;
    const float hv = ov * tanhf(cn);
    cst[(size_t)bb * H_ + hcol] = cn;
    const ushort_t hb = (ushort_t)bfr(hv);
    hnext[(size_t)bb * H_ + hcol] = hb;
    if (layer == 0) h0c[((size_t)bb * TC_ + tl) * H_ + hcol] = hb;
  }
}

// ============================================================================
// Final FC (10 classes) + log_softmax. One wave per batch row; h is bf16.
// ============================================================================
__global__ __launch_bounds__(64) void fc_logsoftmax(
    const ushort_t* __restrict__ h, const float* __restrict__ Wfc,
    const float* __restrict__ bfc, float* __restrict__ out) {
  const int b = blockIdx.x, lane = threadIdx.x;
  const uint4 hv = *(const uint4*)(h + (size_t)b * H_ + lane * 8);
  const float hf[8] = {
      bf2f(hv.x & 0xffffu), bf2f(hv.x >> 16), bf2f(hv.y & 0xffffu), bf2f(hv.y >> 16),
      bf2f(hv.z & 0xffffu), bf2f(hv.z >> 16), bf2f(hv.w & 0xffffu), bf2f(hv.w >> 16)};
  float logits[10];
#pragma unroll
  for (int cc = 0; cc < 10; ++cc) {
    const float* wr = Wfc + (size_t)cc * H_ + lane * 8;
    const float4 w0 = *(const float4*)wr;
    const float4 w1 = *(const float4*)(wr + 4);
    float v = hf[0] * w0.x + hf[1] * w0.y + hf[2] * w0.z + hf[3] * w0.w +
              hf[4] * w1.x + hf[5] * w1.y + hf[6] * w1.z + hf[7] * w1.w;
#pragma unroll
    for (int off = 32; off; off >>= 1) v += __shfl_xor(v, off);
    logits[cc] = v + bfc[cc];
  }
  float m = logits[0];
#pragma unroll
  for (int cc = 1; cc < 10; ++cc) m = fmaxf(m, logits[cc]);
  float s = 0.f;
#pragma unroll
  for (int cc = 0; cc < 10; ++cc) s += __expf(logits[cc] - m);
  const float lse = m + __logf(s);
  if (lane < 10) out[(size_t)b * 10 + lane] = logits[lane] - lse;
}

// ============================================================================
extern "C" void kernel_launch(void* const* d_in, const int* in_sizes, int n_in,
                              void* d_out, int out_size, void* d_ws, size_t ws_size,
                              hipStream_t stream) {
  const float* x    = (const float*)d_in[0];
  const float* Wih0 = (const float*)d_in[1];
  const float* Whh0 = (const float*)d_in[2];
  const float* bih0 = (const float*)d_in[3];
  const float* bhh0 = (const float*)d_in[4];
  const float* Wih1 = (const float*)d_in[5];
  const float* Whh1 = (const float*)d_in[6];
  const float* bih1 = (const float*)d_in[7];
  const float* bhh1 = (const float*)d_in[8];
  const float* Wfc  = (const float*)d_in[9];
  const float* bfc  = (const float*)d_in[10];

  float* ws = (float*)d_ws;
  ushort_t* XG0 = (ushort_t*)(ws + OFF_XG0);
  ushort_t* XG1 = (ushort_t*)(ws + OFF_XG1);
  ushort_t* h0c = (ushort_t*)(ws + OFF_H0C);
  ushort_t* hb0 = (ushort_t*)(ws + OFF_HB0);
  ushort_t* hb1 = (ushort_t*)(ws + OFF_HB1);
  float* c0 = ws + OFF_C0;
  float* c1 = ws + OFF_C1;
  short8v* wf0 = (short8v*)(ws + OFF_WF0);
  short8v* wf1 = (short8v*)(ws + OFF_WF1);
  short8v* wi0 = (short8v*)(ws + OFF_WI0);
  short8v* wi1 = (short8v*)(ws + OFF_WI1);

  // zero h ping-pongs + c states; pack all weights to MFMA fragments
  hipMemsetAsync(hb0, 0, (OFF_WF0 - OFF_HB0) * sizeof(float), stream);
  pack_whh3<<<512, 256, 0, stream>>>(Whh0, (uint4*)wf0);
  pack_whh3<<<512, 256, 0, stream>>>(Whh1, (uint4*)wf1);
  pack_wih<<<256, 256, 0, stream>>>(Wih0, (uint4*)wi0, IN_);
  pack_wih<<<512, 256, 0, stream>>>(Wih1, (uint4*)wi1, H_);

  const size_t BHu = (size_t)B_ * H_;  // bf16 slot stride
  for (int ch = 0; ch < NCHUNK_; ++ch) {
    const int t0 = ch * TC_;
    // one GEMM dispatch per chunk: XG1(ch-1) from h0c (if ch>0) + XG0(ch)
    const int do1 = (ch > 0) ? 1 : 0;
    gemm_dual<<<do1 ? 2048 : 1024, 256, 0, stream>>>(
        x, wi0, bih0, bhh0, XG0, t0,
        h0c, wi1, bih1, bhh1, XG1, do1);
    for (int t = 0; t < TC_; ++t) {
      const int sg0 = t0 + t + 1;        // L0 global step (1-based)
      const int sg1 = sg0 - TC_;         // L1 global step (prev chunk)
      const int mode = (ch == 0) ? 1 : 0;
      const int nblk = (ch == 0) ? 256 : 512;
      lstm_step2<<<nblk, 256, 0, stream>>>(
          wf0, XG0, hb0 + ((sg0 - 1) & 1) * BHu, hb0 + (sg0 & 1) * BHu, c0, h0c,
          wf1, XG1, hb1 + ((sg1 - 1) & 1) * BHu, hb1 + (sg1 & 1) * BHu, c1,
          t, mode);
    }
  }
  // pipeline drain: XG1(15) then L1-only steps over the last chunk
  gemm_dual<<<1024, 256, 0, stream>>>(
      x, wi0, bih0, bhh0, XG0, -1,       // t0<0 unused: grid covers XG1 only
      h0c, wi1, bih1, bhh1, XG1, 1);
  for (int t = 0; t < TC_; ++t) {
    const int sg1 = (NCHUNK_ - 1) * TC_ + t + 1;
    lstm_step2<<<256, 256, 0, stream>>>(
        wf0, XG0, hb0, hb0, c0, h0c,
        wf1, XG1, hb1 + ((sg1 - 1) & 1) * BHu, hb1 + (sg1 & 1) * BHu, c1,
        t, 2);
  }
  // T=256 even -> final h1 in bf16 slot 0
  fc_logsoftmax<<<dim3(B_), 64, 0, stream>>>(hb1, Wfc, bfc, (float*)d_out);
}